// Round 10
// baseline (188.817 us; speedup 1.0000x reference)
//
#include <hip/hip_runtime.h>

// DIM=256 H=8 HD=32 W=64 N=8192 nw=128
// xyz: T=40, off=20, hi=39 ; rgb: T=32, off=16, hi=31
// table element ((c*T+t)*8+h)*32+d == r*256 + h*32 + d, r=c*T+t

typedef __attribute__((ext_vector_type(8))) short short8;
typedef __attribute__((ext_vector_type(4))) float f32x4;

__device__ __forceinline__ unsigned short f2bf(float f) {
    union { float f; unsigned int u; } v; v.f = f;
    unsigned int r = v.u + 0x7FFFu + ((v.u >> 16) & 1u);
    return (unsigned short)(r >> 16);
}

// Wave-local ordering fence: drains this wave's outstanding DS ops.
#define LFENCE() asm volatile("s_waitcnt lgkmcnt(0)" ::: "memory")

// ---------------------------------------------------------------------------
// Round-18: merge k_bias + k_av -> k_attn. r8/r9 post-mortem: per-dispatch
// wins (k_av 51.7 -> <43us) no longer move wall-clock — the remaining cost
// is launch structure: 5 serialized launches, 33MB lgt roundtrip, duplicate
// q_s/cwf/idxp work, inter-launch drains. Merge the two attention kernels:
// r3 monolith skeleton + ALL fixes (int atomics, 3-component batched units,
// packed idxp shared by dk/dq gathers, f32x4 zeroing). dk gathers cross-wave
// (2 barriers per half — cheap batched). LDS 57.9KB -> 2 blocks/CU = reg
// limit anyway. lgt GONE. 4 launches total.
// Prediction: k_attn 45-55us, total ~135-142. Flat again => harness floor.
// ---------------------------------------------------------------------------
__global__ __launch_bounds__(256) void k_cast(
    const float* __restrict__ feats, const float* __restrict__ qkvw,
    const float* __restrict__ pw,
    ushort* __restrict__ fb, ushort* __restrict__ qwb, ushort* __restrict__ pwb)
{
    int t = blockIdx.x * 256 + threadIdx.x;   // each thread casts 8 floats
    const float* src; ushort* dst; int off;
    if (t < 262144)            { src = feats; dst = fb;  off = t; }
    else if (t < 286720)       { src = qkvw;  dst = qwb; off = t - 262144; }
    else                       { src = pw;    dst = pwb; off = t - 286720; }
    const float* s = src + (size_t)off * 8;
    float4 v0 = *(const float4*)s, v1 = *(const float4*)(s + 4);
    union { ushort u[8]; uint4 v; } pk;
    pk.u[0] = f2bf(v0.x); pk.u[1] = f2bf(v0.y); pk.u[2] = f2bf(v0.z); pk.u[3] = f2bf(v0.w);
    pk.u[4] = f2bf(v1.x); pk.u[5] = f2bf(v1.y); pk.u[6] = f2bf(v1.z); pk.u[7] = f2bf(v1.w);
    *(uint4*)(dst + (size_t)off * 8) = pk.v;
}

// ---------------------------------------------------------------------------
// QKV GEMM, 64x64 tiles, pure-bf16 staging. (unchanged)
// ---------------------------------------------------------------------------
__global__ __launch_bounds__(256) void k_qkv(
    const ushort* __restrict__ A, const ushort* __restrict__ B,
    const float* __restrict__ bias,
    ushort* __restrict__ qb, ushort* __restrict__ kb, ushort* __restrict__ vb)
{
    __shared__ __align__(16) ushort a_s[64 * 72];
    __shared__ __align__(16) ushort b_s[64 * 72];
    const int tid = threadIdx.x;
    const int m0 = blockIdx.y * 64;
    const int n0 = blockIdx.x * 64;
    const int w = tid >> 6, wm = w >> 1, wn = w & 1;
    const int l4 = tid & 15, quad = (tid >> 4) & 3;
    f32x4 acc[2][2];
#pragma unroll
    for (int mt = 0; mt < 2; ++mt)
#pragma unroll
        for (int nt = 0; nt < 2; ++nt) acc[mt][nt] = (f32x4){0.f, 0.f, 0.f, 0.f};

    for (int k0 = 0; k0 < 256; k0 += 64) {
#pragma unroll
        for (int l = 0; l < 2; ++l) {
            int e = tid + l * 256;
            int row = e >> 3, kq = e & 7;
            *(uint4*)&a_s[row * 72 + kq * 8] =
                *(const uint4*)(A + (size_t)(m0 + row) * 256 + k0 + kq * 8);
            *(uint4*)&b_s[row * 72 + kq * 8] =
                *(const uint4*)(B + (size_t)(n0 + row) * 256 + k0 + kq * 8);
        }
        __syncthreads();
#pragma unroll
        for (int kh = 0; kh < 2; ++kh) {
            short8 bf0 = *(const short8*)&b_s[(wn * 32 + l4) * 72 + kh * 32 + quad * 8];
            short8 bf1 = *(const short8*)&b_s[(wn * 32 + 16 + l4) * 72 + kh * 32 + quad * 8];
#pragma unroll
            for (int mt = 0; mt < 2; ++mt) {
                short8 af = *(const short8*)&a_s[(wm * 32 + mt * 16 + l4) * 72 + kh * 32 + quad * 8];
                acc[mt][0] = __builtin_amdgcn_mfma_f32_16x16x32_bf16(af, bf0, acc[mt][0], 0, 0, 0);
                acc[mt][1] = __builtin_amdgcn_mfma_f32_16x16x32_bf16(af, bf1, acc[mt][1], 0, 0, 0);
            }
        }
        __syncthreads();
    }
#pragma unroll
    for (int nt = 0; nt < 2; ++nt) {
        int c = n0 + wn * 32 + nt * 16 + l4;
        float bv = bias[c];
        int s = c >> 8, rem = c & 255, h = rem >> 5, d = rem & 31;
        ushort* dst = (s == 0) ? qb : ((s == 1) ? kb : vb);
        float mul = (s == 0) ? 0.17677669529663687f : 1.0f;
#pragma unroll
        for (int mt = 0; mt < 2; ++mt) {
            int mbase = m0 + wm * 32 + mt * 16 + quad * 4;
#pragma unroll
            for (int reg = 0; reg < 4; ++reg) {
                int m = mbase + reg;
                int nw = m >> 6, ii = m & 63;
                dst[((size_t)((nw * 8 + h) * 64 + ii)) * 32 + d] = f2bf((acc[mt][nt][reg] + bv) * mul);
            }
        }
    }
}

// ---------------------------------------------------------------------------
// Merged attention kernel.
// ---------------------------------------------------------------------------
#define DBS 44
#define SL3 132          // 3 slices of 44
#define FXS 16777216.0f
#define FXI (1.0f / 16777216.0f)

__global__ __launch_bounds__(256, 2) void k_attn(
    const ushort* __restrict__ qb, const ushort* __restrict__ kb, const ushort* __restrict__ vb,
    const float* __restrict__ nco,
    const float* __restrict__ qxt, const float* __restrict__ kxt, const float* __restrict__ vxt,
    const float* __restrict__ qrt, const float* __restrict__ krt, const float* __restrict__ vrt,
    ushort* __restrict__ aout)
{
    __shared__ __align__(16) float dbuf[64 * SL3];   // 33,792 B: 3 c-slices of 44
    __shared__ __align__(16) ushort U[11264];        // 22,528 B overlay region
    __shared__ __align__(16) float cwf[64 * 6];      //  1,536 B (57.9 KB total)
    // Phase A overlays:
    ushort* q_s  = U;              // [64][40] = 2560
    ushort* k_s  = U + 2560;       // [64][40] = 2560, ends 5120
    ushort* tbl  = U + 5120;       // [128][40] = 5120, ends 10240
    // Phase B overlays:
    ushort* attn_s = U;            // [64][72] = 4608
    ushort* v_t    = U + 4608;     // [32][72] = 2304, ends 6912
    ushort* vtbl   = U + 6912;     // [32][136] = 4352, ends 11264

    const int tid = threadIdx.x;
    const int n = blockIdx.x >> 3;
    const int h = blockIdx.x & 7;
    const int w = tid >> 6;
    const int lane = tid & 63;
    const int l4 = tid & 15;
    const int quad = (tid >> 4) & 3;

    const size_t base = (size_t)((n * 8 + h) * 64) * 32;

    // ---- stage q, k, coords ----
    {
        int row = tid >> 2, part = tid & 3;
        *(uint4*)&q_s[row * 40 + part * 8] = *(const uint4*)(qb + base + tid * 8);
        *(uint4*)&k_s[row * 40 + part * 8] = *(const uint4*)(kb + base + tid * 8);
    }
    if (tid < 64) {
        const float* cp = nco + (size_t)(n * 64 + tid) * 6;
        cwf[tid * 6 + 0] = cp[0] * 4.f; cwf[tid * 6 + 1] = cp[1] * 4.f;
        cwf[tid * 6 + 2] = cp[2] * 4.f; cwf[tid * 6 + 3] = cp[3] * 8.f;
        cwf[tid * 6 + 4] = cp[4] * 8.f; cwf[tid * 6 + 5] = cp[5] * 8.f;
    }

    auto stageTbl = [&](const float* tbg, int R, int Rpad) {
        for (int e = tid; e < R * 4; e += 256) {
            int r = e >> 2, part = e & 3;
            const float* src = tbg + (size_t)r * 256 + part * 8;
            float4 f0 = *(const float4*)src, f1 = *(const float4*)(src + 4);
            union { ushort u[8]; uint4 v; } pk;
            pk.u[0] = f2bf(f0.x); pk.u[1] = f2bf(f0.y); pk.u[2] = f2bf(f0.z); pk.u[3] = f2bf(f0.w);
            pk.u[4] = f2bf(f1.x); pk.u[5] = f2bf(f1.y); pk.u[6] = f2bf(f1.z); pk.u[7] = f2bf(f1.w);
            *(uint4*)&tbl[r * 40 + part * 8] = pk.v;
        }
        for (int e = tid; e < (Rpad - R) * 40; e += 256) tbl[R * 40 + e] = 0;
    };
    auto stageVtbl = [&](const float* tbg, int R) {
        for (int e = tid; e < R * 4; e += 256) {
            int r = e >> 2, part = e & 3;
            const float* src = tbg + (size_t)r * 256 + part * 8;
            float4 f0 = *(const float4*)src, f1 = *(const float4*)(src + 4);
            int d0 = part * 8;
            vtbl[(d0 + 0) * 136 + r] = f2bf(f0.x);
            vtbl[(d0 + 1) * 136 + r] = f2bf(f0.y);
            vtbl[(d0 + 2) * 136 + r] = f2bf(f0.z);
            vtbl[(d0 + 3) * 136 + r] = f2bf(f0.w);
            vtbl[(d0 + 4) * 136 + r] = f2bf(f1.x);
            vtbl[(d0 + 5) * 136 + r] = f2bf(f1.y);
            vtbl[(d0 + 6) * 136 + r] = f2bf(f1.z);
            vtbl[(d0 + 7) * 136 + r] = f2bf(f1.w);
        }
    };
    auto stageVt = [&]() {
        int j = tid >> 2, d0 = (tid & 3) * 8;
        uint4 pk = *(const uint4*)(vb + base + tid * 8);
        const ushort* u = (const ushort*)&pk;
#pragma unroll
        for (int ii = 0; ii < 8; ++ii) v_t[(d0 + ii) * 72 + j] = u[ii];
    };

    stageTbl(kxt + h * 32, 120, 128);
    __syncthreads();

    // ---- packed bin indices: x = floor(c_i(own r) - c_j(col tt,l4)) + off ----
    // Shared by dk-gather (reads row j) and dq-gather (reads row i).
    unsigned idxp[24];
#pragma unroll
    for (int c6 = 0; c6 < 6; ++c6) {
        const int off = (c6 < 3) ? 20 : 16, hi = (c6 < 3) ? 39 : 31;
        float co0 = cwf[(w * 16 + quad * 4 + 0) * 6 + c6];
        float co1 = cwf[(w * 16 + quad * 4 + 1) * 6 + c6];
        float co2 = cwf[(w * 16 + quad * 4 + 2) * 6 + c6];
        float co3 = cwf[(w * 16 + quad * 4 + 3) * 6 + c6];
#pragma unroll
        for (int tt = 0; tt < 4; ++tt) {
            float cj = cwf[(tt * 16 + l4) * 6 + c6];
            unsigned p = (unsigned)min(max((int)floorf(co0 - cj) + off, 0), hi);
            p |= (unsigned)min(max((int)floorf(co1 - cj) + off, 0), hi) << 8;
            p |= (unsigned)min(max((int)floorf(co2 - cj) + off, 0), hi) << 16;
            p |= (unsigned)min(max((int)floorf(co3 - cj) + off, 0), hi) << 24;
            idxp[c6 * 4 + tt] = p;
        }
    }

    float lg[4][4];   // row i = w*16+quad*4+reg (own), col j = tt*16+l4

    // ---- QK logits ----
    {
        short8 aq = *(const short8*)&q_s[(w * 16 + l4) * 40 + quad * 8];
#pragma unroll
        for (int tt = 0; tt < 4; ++tt) {
            short8 bk = *(const short8*)&k_s[(tt * 16 + l4) * 40 + quad * 8];
            f32x4 r = {0.f, 0.f, 0.f, 0.f};
            r = __builtin_amdgcn_mfma_f32_16x16x32_bf16(aq, bk, r, 0, 0, 0);
            lg[tt][0] = r[0]; lg[tt][1] = r[1]; lg[tt][2] = r[2]; lg[tt][3] = r[3];
        }
    }

    int ibase[4];
#pragma unroll
    for (int r = 0; r < 4; ++r) ibase[r] = (w * 16 + quad * 4 + r) * SL3;

    // 3-component table-GEMM into dbuf slices (own rows).
    auto tgemm3 = [&](const ushort* a_sp, int T) {
        short8 af = *(const short8*)&a_sp[(w * 16 + l4) * 40 + quad * 8];
        const int NT = (T == 40) ? 3 : 2;
        int rb = w * 16 + quad * 4;
#pragma unroll
        for (int c = 0; c < 3; ++c) {
            for (int tt = 0; tt < NT; ++tt) {
                short8 bf = *(const short8*)&tbl[(c * T + tt * 16 + l4) * 40 + quad * 8];
                f32x4 a = {0.f, 0.f, 0.f, 0.f};
                a = __builtin_amdgcn_mfma_f32_16x16x32_bf16(af, bf, a, 0, 0, 0);
                int col = tt * 16 + l4;
                if (col < T) {
                    int sc = c * DBS + col;
                    dbuf[(rb + 0) * SL3 + sc] = a[0];
                    dbuf[(rb + 1) * SL3 + sc] = a[1];
                    dbuf[(rb + 2) * SL3 + sc] = a[2];
                    dbuf[(rb + 3) * SL3 + sc] = a[3];
                }
            }
        }
    };
    // dk-gather: bias_k[i,j] += dk[j, x(i,j)] -> reads row j (cross-wave)
    auto gatherK3 = [&](int half) {
#pragma unroll
        for (int c = 0; c < 3; ++c) {
#pragma unroll
            for (int tt = 0; tt < 4; ++tt) {
                unsigned p = idxp[(half * 3 + c) * 4 + tt];
                int jb = (tt * 16 + l4) * SL3 + c * DBS;
#pragma unroll
                for (int r = 0; r < 4; ++r) {
                    int x = (p >> (8 * r)) & 255;
                    lg[tt][r] += dbuf[jb + x];
                }
            }
        }
    };
    // dq-gather: bias_q[i,j] += dq[i, x(i,j)] -> reads own row i
    auto gatherQ3 = [&](int half) {
#pragma unroll
        for (int c = 0; c < 3; ++c) {
#pragma unroll
            for (int tt = 0; tt < 4; ++tt) {
                unsigned p = idxp[(half * 3 + c) * 4 + tt];
#pragma unroll
                for (int r = 0; r < 4; ++r) {
                    int x = (p >> (8 * r)) & 255;
                    lg[tt][r] += dbuf[ibase[r] + c * DBS + x];
                }
            }
        }
    };
    auto scatter3 = [&](int half) {
        unsigned* bb = (unsigned*)dbuf;
#pragma unroll
        for (int c = 0; c < 3; ++c) {
#pragma unroll
            for (int tt = 0; tt < 4; ++tt) {
                unsigned p = idxp[(half * 3 + c) * 4 + tt];
#pragma unroll
                for (int r = 0; r < 4; ++r) {
                    int x = (p >> (8 * r)) & 255;
                    unsigned q = (unsigned)(lg[tt][r] * FXS + 0.5f);
                    atomicAdd(&bb[ibase[r] + c * DBS + x], q);
                }
            }
        }
    };
    auto zeroAll = [&]() {
        float4 z = {0.f, 0.f, 0.f, 0.f};
        float4* rb = (float4*)&dbuf[w * 16 * SL3];     // 16*132 = 2112 f = 528 f4
        for (int v = lane; v < 528; v += 64) rb[v] = z;
    };

    // ---- bias_k xyz ----
    tgemm3(k_s, 40);
    __syncthreads();                       // dk visible to all waves
    gatherK3(0);
    __syncthreads();                       // all done reading dbuf + tbl(kxt)
    stageTbl(krt + h * 32, 96, 96);
    __syncthreads();
    // ---- bias_k rgb ----
    tgemm3(k_s, 32);
    __syncthreads();
    gatherK3(1);
    __syncthreads();
    stageTbl(qxt + h * 32, 120, 128);
    __syncthreads();
    // ---- bias_q xyz ----
    tgemm3(q_s, 40);
    __syncthreads();                       // own dbuf writes drained; tbl reads done
    gatherQ3(0);                           // own rows
    stageTbl(qrt + h * 32, 96, 96);        // concurrent: disjoint memory
    __syncthreads();
    // ---- bias_q rgb ----
    tgemm3(q_s, 32);
    __syncthreads();                       // q_s/k_s/tbl die here
    gatherQ3(1);
    stageVtbl(vxt + h * 32, 120);
    stageVt();
    __syncthreads();

    // ---- softmax ----
#pragma unroll
    for (int reg = 0; reg < 4; ++reg) {
        float m = fmaxf(fmaxf(lg[0][reg], lg[1][reg]), fmaxf(lg[2][reg], lg[3][reg]));
        m = fmaxf(m, __shfl_xor(m, 1));
        m = fmaxf(m, __shfl_xor(m, 2));
        m = fmaxf(m, __shfl_xor(m, 4));
        m = fmaxf(m, __shfl_xor(m, 8));
        float s = 0.f;
#pragma unroll
        for (int tt = 0; tt < 4; ++tt) { lg[tt][reg] = __expf(lg[tt][reg] - m); s += lg[tt][reg]; }
        s += __shfl_xor(s, 1); s += __shfl_xor(s, 2);
        s += __shfl_xor(s, 4); s += __shfl_xor(s, 8);
        float inv = 1.f / s;
#pragma unroll
        for (int tt = 0; tt < 4; ++tt) lg[tt][reg] *= inv;
    }
#pragma unroll
    for (int tt = 0; tt < 4; ++tt)
#pragma unroll
        for (int reg = 0; reg < 4; ++reg)
            attn_s[(w * 16 + quad * 4 + reg) * 72 + tt * 16 + l4] = f2bf(lg[tt][reg]);
    zeroAll();
    __syncthreads();

    // ---- AV ----
    f32x4 acc0 = {0.f, 0.f, 0.f, 0.f}, acc1 = {0.f, 0.f, 0.f, 0.f};
#pragma unroll
    for (int s = 0; s < 2; ++s) {
        short8 af = *(const short8*)&attn_s[(w * 16 + l4) * 72 + s * 32 + quad * 8];
        short8 b0 = *(const short8*)&v_t[l4 * 72 + s * 32 + quad * 8];
        short8 b1 = *(const short8*)&v_t[(16 + l4) * 72 + s * 32 + quad * 8];
        acc0 = __builtin_amdgcn_mfma_f32_16x16x32_bf16(af, b0, acc0, 0, 0, 0);
        acc1 = __builtin_amdgcn_mfma_f32_16x16x32_bf16(af, b1, acc1, 0, 0, 0);
    }

    // 3-component value-bias: fixed-point bins x vtbl.
    auto atgemm3 = [&](int T, int S) {
        int rowb = (w * 16 + l4) * SL3;
#pragma unroll
        for (int c = 0; c < 3; ++c) {
#pragma unroll
            for (int s = 0; s < S; ++s) {
                int koff = s * 32 + quad * 8;
                short8 af = {0, 0, 0, 0, 0, 0, 0, 0};
                int kr = 0;
                if (koff < T) {
                    const unsigned* ap = (const unsigned*)&dbuf[rowb + c * DBS + koff];
                    uint4 u0 = *(const uint4*)ap;
                    uint4 u1 = *(const uint4*)(ap + 4);
                    af[0] = (short)f2bf((float)u0.x * FXI); af[1] = (short)f2bf((float)u0.y * FXI);
                    af[2] = (short)f2bf((float)u0.z * FXI); af[3] = (short)f2bf((float)u0.w * FXI);
                    af[4] = (short)f2bf((float)u1.x * FXI); af[5] = (short)f2bf((float)u1.y * FXI);
                    af[6] = (short)f2bf((float)u1.z * FXI); af[7] = (short)f2bf((float)u1.w * FXI);
                    kr = c * T + koff;
                }
                short8 b0 = *(const short8*)&vtbl[l4 * 136 + kr];
                short8 b1 = *(const short8*)&vtbl[(16 + l4) * 136 + kr];
                acc0 = __builtin_amdgcn_mfma_f32_16x16x32_bf16(af, b0, acc0, 0, 0, 0);
                acc1 = __builtin_amdgcn_mfma_f32_16x16x32_bf16(af, b1, acc1, 0, 0, 0);
            }
        }
    };

    // ---- value-bias xyz ----
    scatter3(0); LFENCE();
    atgemm3(40, 2);
    __syncthreads();                       // all waves done reading vtbl(vxt)
    zeroAll();
    stageVtbl(vrt + h * 32, 96);
    __syncthreads();
    // ---- value-bias rgb ----
    scatter3(1); LFENCE();
    atgemm3(32, 1);

    // ---- epilogue: bf16 ao[i][h*32+d] ----
    {
        ushort* op = aout + (size_t)(n * 64 + w * 16 + quad * 4) * 256 + h * 32;
#pragma unroll
        for (int reg = 0; reg < 4; ++reg) {
            op[reg * 256 + l4] = f2bf(acc0[reg]);
            op[reg * 256 + 16 + l4] = f2bf(acc1[reg]);
        }
    }
}

// ---------------------------------------------------------------------------
// Proj GEMM, 64x64 tiles, pure-bf16 staging (pwb precast). (unchanged)
// ---------------------------------------------------------------------------
__global__ __launch_bounds__(256) void k_proj(
    const ushort* __restrict__ A, const ushort* __restrict__ B,
    const float* __restrict__ bias, float* __restrict__ out)
{
    __shared__ __align__(16) ushort a_s[64 * 72];
    __shared__ __align__(16) ushort b_s[64 * 72];
    const int tid = threadIdx.x;
    const int m0 = blockIdx.y * 64;
    const int n0 = blockIdx.x * 64;
    const int w = tid >> 6, wm = w >> 1, wn = w & 1;
    const int l4 = tid & 15, quad = (tid >> 4) & 3;
    f32x4 acc[2][2];
#pragma unroll
    for (int mt = 0; mt < 2; ++mt)
#pragma unroll
        for (int nt = 0; nt < 2; ++nt) acc[mt][nt] = (f32x4){0.f, 0.f, 0.f, 0.f};

    for (int k0 = 0; k0 < 256; k0 += 64) {
#pragma unroll
        for (int l = 0; l < 2; ++l) {
            int e = tid + l * 256;
            int row = e >> 3, kq = e & 7;
            *(uint4*)&a_s[row * 72 + kq * 8] =
                *(const uint4*)(A + (size_t)(m0 + row) * 256 + k0 + kq * 8);
            *(uint4*)&b_s[row * 72 + kq * 8] =
                *(const uint4*)(B + (size_t)(n0 + row) * 256 + k0 + kq * 8);
        }
        __syncthreads();
#pragma unroll
        for (int kh = 0; kh < 2; ++kh) {
            short8 bf0 = *(const short8*)&b_s[(wn * 32 + l4) * 72 + kh * 32 + quad * 8];
            short8 bf1 = *(const short8*)&b_s[(wn * 32 + 16 + l4) * 72 + kh * 32 + quad * 8];
#pragma unroll
            for (int mt = 0; mt < 2; ++mt) {
                short8 af = *(const short8*)&a_s[(wm * 32 + mt * 16 + l4) * 72 + kh * 32 + quad * 8];
                acc[mt][0] = __builtin_amdgcn_mfma_f32_16x16x32_bf16(af, bf0, acc[mt][0], 0, 0, 0);
                acc[mt][1] = __builtin_amdgcn_mfma_f32_16x16x32_bf16(af, bf1, acc[mt][1], 0, 0, 0);
            }
        }
        __syncthreads();
    }
#pragma unroll
    for (int nt = 0; nt < 2; ++nt) {
        int c = n0 + wn * 32 + nt * 16 + l4;
        float bv = bias[c];
#pragma unroll
        for (int mt = 0; mt < 2; ++mt) {
            int mbase = m0 + wm * 32 + mt * 16 + quad * 4;
#pragma unroll
            for (int reg = 0; reg < 4; ++reg)
                out[(size_t)(mbase + reg) * 256 + c] = acc[mt][nt][reg] + bv;
        }
    }
}

extern "C" void kernel_launch(void* const* d_in, const int* in_sizes, int n_in,
                              void* d_out, int out_size, void* d_ws, size_t ws_size,
                              hipStream_t stream)
{
    const float* feats = (const float*)d_in[0];
    const float* nco   = (const float*)d_in[1];
    const float* qkvw  = (const float*)d_in[2];
    const float* qkvb  = (const float*)d_in[3];
    const float* qxt   = (const float*)d_in[4];
    const float* kxt   = (const float*)d_in[5];
    const float* vxt   = (const float*)d_in[6];
    const float* qrt   = (const float*)d_in[7];
    const float* krt   = (const float*)d_in[8];
    const float* vrt   = (const float*)d_in[9];
    const float* pw    = (const float*)d_in[10];
    const float* pb    = (const float*)d_in[11];
    float* out = (float*)d_out;

    ushort* qb  = (ushort*)d_ws;                       // [128][8][64][32] bf16, 4 MB
    ushort* kb  = qb + (size_t)2097152;
    ushort* vb  = kb + (size_t)2097152;
    ushort* aob = vb + (size_t)2097152;                // [8192][256] bf16, 4 MB
    ushort* fb  = aob + (size_t)2097152;               // feats bf16, 4 MB
    ushort* qwb = fb + (size_t)2097152;                // qkv_w bf16, 384 KB
    ushort* pwb = qwb + (size_t)196608;                // proj_w bf16, 128 KB

    k_cast<<<dim3(1152), 256, 0, stream>>>(feats, qkvw, pw, fb, qwb, pwb);
    k_qkv<<<dim3(12, 128), 256, 0, stream>>>(fb, qwb, qkvb, qb, kb, vb);
    k_attn<<<dim3(1024), 256, 0, stream>>>(qb, kb, vb, nco, qxt, kxt, vxt, qrt, krt, vrt, aob);
    k_proj<<<dim3(4, 128), 256, 0, stream>>>(aob, pwb, pb, out);
}

// Round 11
// 147.508 us; speedup vs baseline: 1.2800x; 1.2800x over previous
//
#include <hip/hip_runtime.h>

// DIM=256 H=8 HD=32 W=64 N=8192 nw=128
// xyz: T=40, off=20, hi=39 ; rgb: T=32, off=16, hi=31
// table element ((c*T+t)*8+h)*32+d == r*256 + h*32 + d, r=c*T+t

typedef __attribute__((ext_vector_type(8))) short short8;
typedef __attribute__((ext_vector_type(4))) float f32x4;

__device__ __forceinline__ unsigned short f2bf(float f) {
    union { float f; unsigned int u; } v; v.f = f;
    unsigned int r = v.u + 0x7FFFu + ((v.u >> 16) & 1u);
    return (unsigned short)(r >> 16);
}

// Wave-local ordering fence: drains this wave's outstanding DS ops.
#define LFENCE() asm volatile("s_waitcnt lgkmcnt(0)" ::: "memory")

// ---------------------------------------------------------------------------
// Round-19: REVERT to r9 (149.1us proven). r10's merged k_attn spilled
// (WRITE 78MB, FETCH 45MB — the r1/r4 signature): merged live state
// (lg+acc+idxp+temps) exceeds the 256-reg unified cap -> allocator spill;
// also the split's cross-dispatch overlap (k_bias[b+1] || k_av[b]) is lost
// when merged. Ledger of falsified consolidation attempts: r1/r4 (reg caps),
// r10 (launch merge). The split + int-atomics + batched-fences config is
// the best verified point; restoring it.
// ---------------------------------------------------------------------------
__global__ __launch_bounds__(256) void k_cast(
    const float* __restrict__ feats, const float* __restrict__ qkvw,
    const float* __restrict__ pw,
    ushort* __restrict__ fb, ushort* __restrict__ qwb, ushort* __restrict__ pwb)
{
    int t = blockIdx.x * 256 + threadIdx.x;   // each thread casts 8 floats
    const float* src; ushort* dst; int off;
    if (t < 262144)            { src = feats; dst = fb;  off = t; }
    else if (t < 286720)       { src = qkvw;  dst = qwb; off = t - 262144; }
    else                       { src = pw;    dst = pwb; off = t - 286720; }
    const float* s = src + (size_t)off * 8;
    float4 v0 = *(const float4*)s, v1 = *(const float4*)(s + 4);
    union { ushort u[8]; uint4 v; } pk;
    pk.u[0] = f2bf(v0.x); pk.u[1] = f2bf(v0.y); pk.u[2] = f2bf(v0.z); pk.u[3] = f2bf(v0.w);
    pk.u[4] = f2bf(v1.x); pk.u[5] = f2bf(v1.y); pk.u[6] = f2bf(v1.z); pk.u[7] = f2bf(v1.w);
    *(uint4*)(dst + (size_t)off * 8) = pk.v;
}

// ---------------------------------------------------------------------------
// QKV GEMM, 64x64 tiles, pure-bf16 staging.
// ---------------------------------------------------------------------------
__global__ __launch_bounds__(256) void k_qkv(
    const ushort* __restrict__ A, const ushort* __restrict__ B,
    const float* __restrict__ bias,
    ushort* __restrict__ qb, ushort* __restrict__ kb, ushort* __restrict__ vb)
{
    __shared__ __align__(16) ushort a_s[64 * 72];
    __shared__ __align__(16) ushort b_s[64 * 72];
    const int tid = threadIdx.x;
    const int m0 = blockIdx.y * 64;
    const int n0 = blockIdx.x * 64;
    const int w = tid >> 6, wm = w >> 1, wn = w & 1;
    const int l4 = tid & 15, quad = (tid >> 4) & 3;
    f32x4 acc[2][2];
#pragma unroll
    for (int mt = 0; mt < 2; ++mt)
#pragma unroll
        for (int nt = 0; nt < 2; ++nt) acc[mt][nt] = (f32x4){0.f, 0.f, 0.f, 0.f};

    for (int k0 = 0; k0 < 256; k0 += 64) {
#pragma unroll
        for (int l = 0; l < 2; ++l) {
            int e = tid + l * 256;
            int row = e >> 3, kq = e & 7;
            *(uint4*)&a_s[row * 72 + kq * 8] =
                *(const uint4*)(A + (size_t)(m0 + row) * 256 + k0 + kq * 8);
            *(uint4*)&b_s[row * 72 + kq * 8] =
                *(const uint4*)(B + (size_t)(n0 + row) * 256 + k0 + kq * 8);
        }
        __syncthreads();
#pragma unroll
        for (int kh = 0; kh < 2; ++kh) {
            short8 bf0 = *(const short8*)&b_s[(wn * 32 + l4) * 72 + kh * 32 + quad * 8];
            short8 bf1 = *(const short8*)&b_s[(wn * 32 + 16 + l4) * 72 + kh * 32 + quad * 8];
#pragma unroll
            for (int mt = 0; mt < 2; ++mt) {
                short8 af = *(const short8*)&a_s[(wm * 32 + mt * 16 + l4) * 72 + kh * 32 + quad * 8];
                acc[mt][0] = __builtin_amdgcn_mfma_f32_16x16x32_bf16(af, bf0, acc[mt][0], 0, 0, 0);
                acc[mt][1] = __builtin_amdgcn_mfma_f32_16x16x32_bf16(af, bf1, acc[mt][1], 0, 0, 0);
            }
        }
        __syncthreads();
    }
#pragma unroll
    for (int nt = 0; nt < 2; ++nt) {
        int c = n0 + wn * 32 + nt * 16 + l4;
        float bv = bias[c];
        int s = c >> 8, rem = c & 255, h = rem >> 5, d = rem & 31;
        ushort* dst = (s == 0) ? qb : ((s == 1) ? kb : vb);
        float mul = (s == 0) ? 0.17677669529663687f : 1.0f;
#pragma unroll
        for (int mt = 0; mt < 2; ++mt) {
            int mbase = m0 + wm * 32 + mt * 16 + quad * 4;
#pragma unroll
            for (int reg = 0; reg < 4; ++reg) {
                int m = mbase + reg;
                int nw = m >> 6, ii = m & 63;
                dst[((size_t)((nw * 8 + h) * 64 + ii)) * 32 + d] = f2bf((acc[mt][nt][reg] + bv) * mul);
            }
        }
    }
}

// ---------------------------------------------------------------------------
// k_bias: logitsT = K.Q^T + bias_k, wave-private gathers (transposed output).
// ---------------------------------------------------------------------------
#define DBS 44
#define SL3 132          // 3 slices of 44
#define FXS 16777216.0f
#define FXI (1.0f / 16777216.0f)

__global__ __launch_bounds__(256, 2) void k_bias(
    const ushort* __restrict__ qb, const ushort* __restrict__ kb,
    const float* __restrict__ nco,
    const float* __restrict__ kxt, const float* __restrict__ krt,
    float* __restrict__ lgt)
{
    __shared__ __align__(16) float dbuf[64 * DBS];
    __shared__ __align__(16) ushort q_s[64 * 40];
    __shared__ __align__(16) ushort k_s[64 * 40];
    __shared__ __align__(16) ushort tbl[128 * 40];
    __shared__ __align__(16) float cwf[64 * 6];

    const int tid = threadIdx.x;
    const int n = blockIdx.x >> 3;
    const int h = blockIdx.x & 7;
    const int w = tid >> 6;
    const int l4 = tid & 15;
    const int quad = (tid >> 4) & 3;

    const size_t base = (size_t)((n * 8 + h) * 64) * 32;

    {
        int row = tid >> 2, part = tid & 3;
        *(uint4*)&q_s[row * 40 + part * 8] = *(const uint4*)(qb + base + tid * 8);
        *(uint4*)&k_s[row * 40 + part * 8] = *(const uint4*)(kb + base + tid * 8);
    }
    if (tid < 64) {
        const float* cp = nco + (size_t)(n * 64 + tid) * 6;
        cwf[tid * 6 + 0] = cp[0] * 4.f; cwf[tid * 6 + 1] = cp[1] * 4.f;
        cwf[tid * 6 + 2] = cp[2] * 4.f; cwf[tid * 6 + 3] = cp[3] * 8.f;
        cwf[tid * 6 + 4] = cp[4] * 8.f; cwf[tid * 6 + 5] = cp[5] * 8.f;
    }

    auto stageTbl = [&](const float* tbg, int R, int Rpad) {
        for (int e = tid; e < R * 4; e += 256) {
            int r = e >> 2, part = e & 3;
            const float* src = tbg + (size_t)r * 256 + part * 8;
            float4 f0 = *(const float4*)src, f1 = *(const float4*)(src + 4);
            union { ushort u[8]; uint4 v; } pk;
            pk.u[0] = f2bf(f0.x); pk.u[1] = f2bf(f0.y); pk.u[2] = f2bf(f0.z); pk.u[3] = f2bf(f0.w);
            pk.u[4] = f2bf(f1.x); pk.u[5] = f2bf(f1.y); pk.u[6] = f2bf(f1.z); pk.u[7] = f2bf(f1.w);
            *(uint4*)&tbl[r * 40 + part * 8] = pk.v;
        }
        for (int e = tid; e < (Rpad - R) * 40; e += 256) tbl[R * 40 + e] = 0;
    };

    float lg[4][4];   // TRANSPOSED: row j = w*16+quad*4+reg, col i = tt*16+l4
    int ibase[4];
#pragma unroll
    for (int r = 0; r < 4; ++r) ibase[r] = (w * 16 + quad * 4 + r) * DBS;

    auto tgemmC = [&](const ushort* a_s, int c, int T) {
        short8 af = *(const short8*)&a_s[(w * 16 + l4) * 40 + quad * 8];
        const int NT = (T == 40) ? 3 : 2;
        for (int tt = 0; tt < NT; ++tt) {
            short8 bf = *(const short8*)&tbl[(c * T + tt * 16 + l4) * 40 + quad * 8];
            f32x4 a = {0.f, 0.f, 0.f, 0.f};
            a = __builtin_amdgcn_mfma_f32_16x16x32_bf16(af, bf, a, 0, 0, 0);
            int col = tt * 16 + l4;
            int rb = w * 16 + quad * 4;
            if (col < T) {
                dbuf[(rb + 0) * DBS + col] = a[0];
                dbuf[(rb + 1) * DBS + col] = a[1];
                dbuf[(rb + 2) * DBS + col] = a[2];
                dbuf[(rb + 3) * DBS + col] = a[3];
            }
        }
    };

    stageTbl(kxt + h * 32, 120, 128);
    __syncthreads();

    unsigned idxp[24];
#pragma unroll
    for (int c6 = 0; c6 < 6; ++c6) {
        const int off = (c6 < 3) ? 20 : 16, hi = (c6 < 3) ? 39 : 31;
        float co0 = cwf[(w * 16 + quad * 4 + 0) * 6 + c6];
        float co1 = cwf[(w * 16 + quad * 4 + 1) * 6 + c6];
        float co2 = cwf[(w * 16 + quad * 4 + 2) * 6 + c6];
        float co3 = cwf[(w * 16 + quad * 4 + 3) * 6 + c6];
#pragma unroll
        for (int tt = 0; tt < 4; ++tt) {
            float ci = cwf[(tt * 16 + l4) * 6 + c6];
            unsigned p = (unsigned)min(max((int)floorf(ci - co0) + off, 0), hi);
            p |= (unsigned)min(max((int)floorf(ci - co1) + off, 0), hi) << 8;
            p |= (unsigned)min(max((int)floorf(ci - co2) + off, 0), hi) << 16;
            p |= (unsigned)min(max((int)floorf(ci - co3) + off, 0), hi) << 24;
            idxp[c6 * 4 + tt] = p;
        }
    }

    auto gatherT = [&](int cc) {
#pragma unroll
        for (int tt = 0; tt < 4; ++tt) {
            unsigned p = idxp[cc * 4 + tt];
#pragma unroll
            for (int r = 0; r < 4; ++r) {
                int x = (p >> (8 * r)) & 255;
                lg[tt][r] += dbuf[ibase[r] + x];
            }
        }
    };

    {
        short8 ak = *(const short8*)&k_s[(w * 16 + l4) * 40 + quad * 8];
#pragma unroll
        for (int tt = 0; tt < 4; ++tt) {
            short8 bq = *(const short8*)&q_s[(tt * 16 + l4) * 40 + quad * 8];
            f32x4 r = {0.f, 0.f, 0.f, 0.f};
            r = __builtin_amdgcn_mfma_f32_16x16x32_bf16(ak, bq, r, 0, 0, 0);
            lg[tt][0] = r[0]; lg[tt][1] = r[1]; lg[tt][2] = r[2]; lg[tt][3] = r[3];
        }
    }

    tgemmC(k_s, 0, 40); LFENCE();
    gatherT(0); LFENCE();
    tgemmC(k_s, 1, 40); LFENCE();
    gatherT(1); LFENCE();
    tgemmC(k_s, 2, 40); LFENCE();
    gatherT(2);
    __syncthreads();
    stageTbl(krt + h * 32, 96, 96);
    __syncthreads();
    tgemmC(k_s, 0, 32); LFENCE();
    gatherT(3); LFENCE();
    tgemmC(k_s, 1, 32); LFENCE();
    gatherT(4); LFENCE();
    tgemmC(k_s, 2, 32); LFENCE();
    gatherT(5);

    {
        float* lp = lgt + (size_t)(n * 8 + h) * 4096;
#pragma unroll
        for (int tt = 0; tt < 4; ++tt)
#pragma unroll
            for (int reg = 0; reg < 4; ++reg)
                lp[(w * 16 + quad * 4 + reg) * 64 + tt * 16 + l4] = lg[tt][reg];
    }
}

// ---------------------------------------------------------------------------
// k_av: 3-component batched fence units, fixed-point native atomics.
// ---------------------------------------------------------------------------
__global__ __launch_bounds__(256, 2) void k_av(
    const ushort* __restrict__ qb, const ushort* __restrict__ vb,
    const float* __restrict__ nco,
    const float* __restrict__ qxt, const float* __restrict__ vxt,
    const float* __restrict__ qrt, const float* __restrict__ vrt,
    const float* __restrict__ lgt,
    ushort* __restrict__ aout)
{
    __shared__ __align__(16) float dbuf[64 * SL3];   // 33,792 B: 3 c-slices of 44
    __shared__ __align__(16) ushort U[11264];        // 22,528 B overlay region
    __shared__ __align__(16) float cwf[64 * 6];      //  1,536 B (57.9 KB total)
    ushort* q_s  = U;              // [64][40]
    ushort* tbl  = U + 2560;       // [128][40]
    ushort* attn_s = U;            // [64][72]
    ushort* v_t    = U + 4608;     // [32][72]
    ushort* vtbl   = U + 6912;     // [32][136]

    const int tid = threadIdx.x;
    const int n = blockIdx.x >> 3;
    const int h = blockIdx.x & 7;
    const int w = tid >> 6;
    const int lane = tid & 63;
    const int l4 = tid & 15;
    const int quad = (tid >> 4) & 3;

    const size_t base = (size_t)((n * 8 + h) * 64) * 32;

    {
        int row = tid >> 2, part = tid & 3;
        *(uint4*)&q_s[row * 40 + part * 8] = *(const uint4*)(qb + base + tid * 8);
    }
    if (tid < 64) {
        const float* cp = nco + (size_t)(n * 64 + tid) * 6;
        cwf[tid * 6 + 0] = cp[0] * 4.f; cwf[tid * 6 + 1] = cp[1] * 4.f;
        cwf[tid * 6 + 2] = cp[2] * 4.f; cwf[tid * 6 + 3] = cp[3] * 8.f;
        cwf[tid * 6 + 4] = cp[4] * 8.f; cwf[tid * 6 + 5] = cp[5] * 8.f;
    }

    auto stageTbl = [&](const float* tbg, int R, int Rpad) {
        for (int e = tid; e < R * 4; e += 256) {
            int r = e >> 2, part = e & 3;
            const float* src = tbg + (size_t)r * 256 + part * 8;
            float4 f0 = *(const float4*)src, f1 = *(const float4*)(src + 4);
            union { ushort u[8]; uint4 v; } pk;
            pk.u[0] = f2bf(f0.x); pk.u[1] = f2bf(f0.y); pk.u[2] = f2bf(f0.z); pk.u[3] = f2bf(f0.w);
            pk.u[4] = f2bf(f1.x); pk.u[5] = f2bf(f1.y); pk.u[6] = f2bf(f1.z); pk.u[7] = f2bf(f1.w);
            *(uint4*)&tbl[r * 40 + part * 8] = pk.v;
        }
        for (int e = tid; e < (Rpad - R) * 40; e += 256) tbl[R * 40 + e] = 0;
    };
    auto stageVtbl = [&](const float* tbg, int R) {
        for (int e = tid; e < R * 4; e += 256) {
            int r = e >> 2, part = e & 3;
            const float* src = tbg + (size_t)r * 256 + part * 8;
            float4 f0 = *(const float4*)src, f1 = *(const float4*)(src + 4);
            int d0 = part * 8;
            vtbl[(d0 + 0) * 136 + r] = f2bf(f0.x);
            vtbl[(d0 + 1) * 136 + r] = f2bf(f0.y);
            vtbl[(d0 + 2) * 136 + r] = f2bf(f0.z);
            vtbl[(d0 + 3) * 136 + r] = f2bf(f0.w);
            vtbl[(d0 + 4) * 136 + r] = f2bf(f1.x);
            vtbl[(d0 + 5) * 136 + r] = f2bf(f1.y);
            vtbl[(d0 + 6) * 136 + r] = f2bf(f1.z);
            vtbl[(d0 + 7) * 136 + r] = f2bf(f1.w);
        }
    };
    auto stageVt = [&]() {
        int j = tid >> 2, d0 = (tid & 3) * 8;
        uint4 pk = *(const uint4*)(vb + base + tid * 8);
        const ushort* u = (const ushort*)&pk;
#pragma unroll
        for (int ii = 0; ii < 8; ++ii) v_t[(d0 + ii) * 72 + j] = u[ii];
    };

    // ---- load logitsT transposed into lg[i own-row][j col] (f32x4) ----
    float lg[4][4];
    {
        const float* lp = lgt + (size_t)(n * 8 + h) * 4096;
        int i0 = w * 16 + quad * 4;
#pragma unroll
        for (int tt = 0; tt < 4; ++tt) {
            f32x4 v = *(const f32x4*)(lp + (size_t)(tt * 16 + l4) * 64 + i0);
            lg[tt][0] = v[0]; lg[tt][1] = v[1]; lg[tt][2] = v[2]; lg[tt][3] = v[3];
        }
    }

    int ibase[4];
#pragma unroll
    for (int r = 0; r < 4; ++r) ibase[r] = (w * 16 + quad * 4 + r) * SL3;

    // 3-component tgemm: stages all of {c=0,1,2} into slices of dbuf.
    auto tgemm3 = [&](int T) {
        short8 af = *(const short8*)&q_s[(w * 16 + l4) * 40 + quad * 8];
        const int NT = (T == 40) ? 3 : 2;
        int rb = w * 16 + quad * 4;
#pragma unroll
        for (int c = 0; c < 3; ++c) {
            for (int tt = 0; tt < NT; ++tt) {
                short8 bf = *(const short8*)&tbl[(c * T + tt * 16 + l4) * 40 + quad * 8];
                f32x4 a = {0.f, 0.f, 0.f, 0.f};
                a = __builtin_amdgcn_mfma_f32_16x16x32_bf16(af, bf, a, 0, 0, 0);
                int col = tt * 16 + l4;
                if (col < T) {
                    int sc = c * DBS + col;
                    dbuf[(rb + 0) * SL3 + sc] = a[0];
                    dbuf[(rb + 1) * SL3 + sc] = a[1];
                    dbuf[(rb + 2) * SL3 + sc] = a[2];
                    dbuf[(rb + 3) * SL3 + sc] = a[3];
                }
            }
        }
    };
    auto zeroAll = [&]() {
        float4 z = {0.f, 0.f, 0.f, 0.f};
        float4* rb = (float4*)&dbuf[w * 16 * SL3];     // 16*132 = 2112 f = 528 f4
        for (int v = lane; v < 528; v += 64) rb[v] = z;
    };

    stageTbl(qxt + h * 32, 120, 128);
    __syncthreads();

    unsigned idxp[24];
#pragma unroll
    for (int c6 = 0; c6 < 6; ++c6) {
        const int off = (c6 < 3) ? 20 : 16, hi = (c6 < 3) ? 39 : 31;
        float co0 = cwf[(w * 16 + quad * 4 + 0) * 6 + c6];
        float co1 = cwf[(w * 16 + quad * 4 + 1) * 6 + c6];
        float co2 = cwf[(w * 16 + quad * 4 + 2) * 6 + c6];
        float co3 = cwf[(w * 16 + quad * 4 + 3) * 6 + c6];
#pragma unroll
        for (int tt = 0; tt < 4; ++tt) {
            float cj = cwf[(tt * 16 + l4) * 6 + c6];
            unsigned p = (unsigned)min(max((int)floorf(co0 - cj) + off, 0), hi);
            p |= (unsigned)min(max((int)floorf(co1 - cj) + off, 0), hi) << 8;
            p |= (unsigned)min(max((int)floorf(co2 - cj) + off, 0), hi) << 16;
            p |= (unsigned)min(max((int)floorf(co3 - cj) + off, 0), hi) << 24;
            idxp[c6 * 4 + tt] = p;
        }
    }

    // 3-component gather: half=0 -> cc 0..2 (xyz), half=1 -> cc 3..5 (rgb)
    auto gather3 = [&](int half) {
#pragma unroll
        for (int c = 0; c < 3; ++c) {
#pragma unroll
            for (int tt = 0; tt < 4; ++tt) {
                unsigned p = idxp[(half * 3 + c) * 4 + tt];
#pragma unroll
                for (int r = 0; r < 4; ++r) {
                    int x = (p >> (8 * r)) & 255;
                    lg[tt][r] += dbuf[ibase[r] + c * DBS + x];
                }
            }
        }
    };
    // 3-component fixed-point scatter: 48 independent ds_add_u32 per thread
    auto scatter3 = [&](int half) {
        unsigned* bb = (unsigned*)dbuf;
#pragma unroll
        for (int c = 0; c < 3; ++c) {
#pragma unroll
            for (int tt = 0; tt < 4; ++tt) {
                unsigned p = idxp[(half * 3 + c) * 4 + tt];
#pragma unroll
                for (int r = 0; r < 4; ++r) {
                    int x = (p >> (8 * r)) & 255;
                    unsigned q = (unsigned)(lg[tt][r] * FXS + 0.5f);
                    atomicAdd(&bb[ibase[r] + c * DBS + x], q);
                }
            }
        }
    };

    // ---- bias_q xyz: one batched unit ----
    tgemm3(40);
    __syncthreads();                       // all waves done reading tbl(qxt) + own dbuf writes drained
    gather3(0);
    stageTbl(qrt + h * 32, 96, 96);
    __syncthreads();
    // ---- bias_q rgb: one batched unit ----
    tgemm3(32);
    __syncthreads();                       // tbl/q_s go dead after this
    gather3(1);
    stageVtbl(vxt + h * 32, 120);
    stageVt();
    __syncthreads();

    // ---- softmax ----
#pragma unroll
    for (int reg = 0; reg < 4; ++reg) {
        float m = fmaxf(fmaxf(lg[0][reg], lg[1][reg]), fmaxf(lg[2][reg], lg[3][reg]));
        m = fmaxf(m, __shfl_xor(m, 1));
        m = fmaxf(m, __shfl_xor(m, 2));
        m = fmaxf(m, __shfl_xor(m, 4));
        m = fmaxf(m, __shfl_xor(m, 8));
        float s = 0.f;
#pragma unroll
        for (int tt = 0; tt < 4; ++tt) { lg[tt][reg] = __expf(lg[tt][reg] - m); s += lg[tt][reg]; }
        s += __shfl_xor(s, 1); s += __shfl_xor(s, 2);
        s += __shfl_xor(s, 4); s += __shfl_xor(s, 8);
        float inv = 1.f / s;
#pragma unroll
        for (int tt = 0; tt < 4; ++tt) lg[tt][reg] *= inv;
    }
#pragma unroll
    for (int tt = 0; tt < 4; ++tt)
#pragma unroll
        for (int reg = 0; reg < 4; ++reg)
            attn_s[(w * 16 + quad * 4 + reg) * 72 + tt * 16 + l4] = f2bf(lg[tt][reg]);
    zeroAll();
    __syncthreads();

    // ---- AV ----
    f32x4 acc0 = {0.f, 0.f, 0.f, 0.f}, acc1 = {0.f, 0.f, 0.f, 0.f};
#pragma unroll
    for (int s = 0; s < 2; ++s) {
        short8 af = *(const short8*)&attn_s[(w * 16 + l4) * 72 + s * 32 + quad * 8];
        short8 b0 = *(const short8*)&v_t[l4 * 72 + s * 32 + quad * 8];
        short8 b1 = *(const short8*)&v_t[(16 + l4) * 72 + s * 32 + quad * 8];
        acc0 = __builtin_amdgcn_mfma_f32_16x16x32_bf16(af, b0, acc0, 0, 0, 0);
        acc1 = __builtin_amdgcn_mfma_f32_16x16x32_bf16(af, b1, acc1, 0, 0, 0);
    }

    // 3-component value-bias contraction: bins (fixed-point u32) x vtbl.
    auto atgemm3 = [&](int T, int S) {
        int rowb = (w * 16 + l4) * SL3;
#pragma unroll
        for (int c = 0; c < 3; ++c) {
#pragma unroll
            for (int s = 0; s < S; ++s) {
                int koff = s * 32 + quad * 8;
                short8 af = {0, 0, 0, 0, 0, 0, 0, 0};
                int kr = 0;
                if (koff < T) {
                    const unsigned* ap = (const unsigned*)&dbuf[rowb + c * DBS + koff];
                    uint4 u0 = *(const uint4*)ap;
                    uint4 u1 = *(const uint4*)(ap + 4);
                    af[0] = (short)f2bf((float)u0.x * FXI); af[1] = (short)f2bf((float)u0.y * FXI);
                    af[2] = (short)f2bf((float)u0.z * FXI); af[3] = (short)f2bf((float)u0.w * FXI);
                    af[4] = (short)f2bf((float)u1.x * FXI); af[5] = (short)f2bf((float)u1.y * FXI);
                    af[6] = (short)f2bf((float)u1.z * FXI); af[7] = (short)f2bf((float)u1.w * FXI);
                    kr = c * T + koff;
                }
                short8 b0 = *(const short8*)&vtbl[l4 * 136 + kr];
                short8 b1 = *(const short8*)&vtbl[(16 + l4) * 136 + kr];
                acc0 = __builtin_amdgcn_mfma_f32_16x16x32_bf16(af, b0, acc0, 0, 0, 0);
                acc1 = __builtin_amdgcn_mfma_f32_16x16x32_bf16(af, b1, acc1, 0, 0, 0);
            }
        }
    };

    // ---- value-bias xyz: one batched unit ----
    scatter3(0); LFENCE();
    atgemm3(40, 2);
    __syncthreads();                       // all waves done reading vtbl(vxt)
    zeroAll();
    stageVtbl(vrt + h * 32, 96);
    __syncthreads();
    // ---- value-bias rgb: one batched unit ----
    scatter3(1); LFENCE();
    atgemm3(32, 1);

    // ---- epilogue: bf16 ao[i][h*32+d] ----
    {
        ushort* op = aout + (size_t)(n * 64 + w * 16 + quad * 4) * 256 + h * 32;
#pragma unroll
        for (int reg = 0; reg < 4; ++reg) {
            op[reg * 256 + l4] = f2bf(acc0[reg]);
            op[reg * 256 + 16 + l4] = f2bf(acc1[reg]);
        }
    }
}

// ---------------------------------------------------------------------------
// Proj GEMM, 64x64 tiles, pure-bf16 staging (pwb precast).
// ---------------------------------------------------------------------------
__global__ __launch_bounds__(256) void k_proj(
    const ushort* __restrict__ A, const ushort* __restrict__ B,
    const float* __restrict__ bias, float* __restrict__ out)
{
    __shared__ __align__(16) ushort a_s[64 * 72];
    __shared__ __align__(16) ushort b_s[64 * 72];
    const int tid = threadIdx.x;
    const int m0 = blockIdx.y * 64;
    const int n0 = blockIdx.x * 64;
    const int w = tid >> 6, wm = w >> 1, wn = w & 1;
    const int l4 = tid & 15, quad = (tid >> 4) & 3;
    f32x4 acc[2][2];
#pragma unroll
    for (int mt = 0; mt < 2; ++mt)
#pragma unroll
        for (int nt = 0; nt < 2; ++nt) acc[mt][nt] = (f32x4){0.f, 0.f, 0.f, 0.f};

    for (int k0 = 0; k0 < 256; k0 += 64) {
#pragma unroll
        for (int l = 0; l < 2; ++l) {
            int e = tid + l * 256;
            int row = e >> 3, kq = e & 7;
            *(uint4*)&a_s[row * 72 + kq * 8] =
                *(const uint4*)(A + (size_t)(m0 + row) * 256 + k0 + kq * 8);
            *(uint4*)&b_s[row * 72 + kq * 8] =
                *(const uint4*)(B + (size_t)(n0 + row) * 256 + k0 + kq * 8);
        }
        __syncthreads();
#pragma unroll
        for (int kh = 0; kh < 2; ++kh) {
            short8 bf0 = *(const short8*)&b_s[(wn * 32 + l4) * 72 + kh * 32 + quad * 8];
            short8 bf1 = *(const short8*)&b_s[(wn * 32 + 16 + l4) * 72 + kh * 32 + quad * 8];
#pragma unroll
            for (int mt = 0; mt < 2; ++mt) {
                short8 af = *(const short8*)&a_s[(wm * 32 + mt * 16 + l4) * 72 + kh * 32 + quad * 8];
                acc[mt][0] = __builtin_amdgcn_mfma_f32_16x16x32_bf16(af, bf0, acc[mt][0], 0, 0, 0);
                acc[mt][1] = __builtin_amdgcn_mfma_f32_16x16x32_bf16(af, bf1, acc[mt][1], 0, 0, 0);
            }
        }
        __syncthreads();
    }
#pragma unroll
    for (int nt = 0; nt < 2; ++nt) {
        int c = n0 + wn * 32 + nt * 16 + l4;
        float bv = bias[c];
#pragma unroll
        for (int mt = 0; mt < 2; ++mt) {
            int mbase = m0 + wm * 32 + mt * 16 + quad * 4;
#pragma unroll
            for (int reg = 0; reg < 4; ++reg)
                out[(size_t)(mbase + reg) * 256 + c] = acc[mt][nt][reg] + bv;
        }
    }
}

extern "C" void kernel_launch(void* const* d_in, const int* in_sizes, int n_in,
                              void* d_out, int out_size, void* d_ws, size_t ws_size,
                              hipStream_t stream)
{
    const float* feats = (const float*)d_in[0];
    const float* nco   = (const float*)d_in[1];
    const float* qkvw  = (const float*)d_in[2];
    const float* qkvb  = (const float*)d_in[3];
    const float* qxt   = (const float*)d_in[4];
    const float* kxt   = (const float*)d_in[5];
    const float* vxt   = (const float*)d_in[6];
    const float* qrt   = (const float*)d_in[7];
    const float* krt   = (const float*)d_in[8];
    const float* vrt   = (const float*)d_in[9];
    const float* pw    = (const float*)d_in[10];
    const float* pb    = (const float*)d_in[11];
    float* out = (float*)d_out;

    ushort* qb  = (ushort*)d_ws;                       // [128][8][64][32] bf16, 4 MB
    ushort* kb  = qb + (size_t)2097152;
    ushort* vb  = kb + (size_t)2097152;
    ushort* aob = vb + (size_t)2097152;                // [8192][256] bf16, 4 MB
    float*  lgt = (float*)(aob + (size_t)2097152);     // [1024][64][64] f32, 16.7 MB
    ushort* fb  = (ushort*)(lgt + (size_t)4194304);    // feats bf16, 4 MB
    ushort* qwb = fb + (size_t)2097152;                // qkv_w bf16, 384 KB
    ushort* pwb = qwb + (size_t)196608;                // proj_w bf16, 128 KB

    k_cast<<<dim3(1152), 256, 0, stream>>>(feats, qkvw, pw, fb, qwb, pwb);
    k_qkv<<<dim3(12, 128), 256, 0, stream>>>(fb, qwb, qkvb, qb, kb, vb);
    k_bias<<<dim3(1024), 256, 0, stream>>>(qb, kb, nco, kxt, krt, lgt);
    k_av<<<dim3(1024), 256, 0, stream>>>(qb, vb, nco, qxt, vxt, qrt, vrt, lgt, aob);
    k_proj<<<dim3(4, 128), 256, 0, stream>>>(aob, pwb, pb, out);
}